// Round 1
// baseline (304.634 us; speedup 1.0000x reference)
//
#include <hip/hip_runtime.h>
#include <hip/hip_bf16.h>

#define DM   512
#define HEADS 8
#define DKH  64
#define BATCH 2
#define SEQ  4096

typedef float  f32x4  __attribute__((ext_vector_type(4)));
typedef __bf16 bf16x8 __attribute__((ext_vector_type(8)));
typedef __bf16 bf16x4 __attribute__((ext_vector_type(4)));

static __device__ __forceinline__ f32x4 mfma16(bf16x8 a, bf16x8 b, f32x4 c) {
    return __builtin_amdgcn_mfma_f32_16x16x32_bf16(a, b, c, 0, 0, 0);
}

// ---------------------------------------------------------------------------
// W [k][n] fp32  ->  Wt [n][k] bf16   (512x512)
// ---------------------------------------------------------------------------
__global__ __launch_bounds__(256) void wt_convert(const float* __restrict__ W,
                                                  __bf16* __restrict__ Wt) {
    __shared__ float tile[32][33];
    const int tx = threadIdx.x & 31, ty = threadIdx.x >> 5;  // ty 0..7
    const int nb = blockIdx.x * 32, kb = blockIdx.y * 32;
#pragma unroll
    for (int i = 0; i < 4; ++i)
        tile[ty + 8 * i][tx] = W[(size_t)(kb + ty + 8 * i) * DM + nb + tx];
    __syncthreads();
#pragma unroll
    for (int i = 0; i < 4; ++i)
        Wt[(size_t)(nb + ty + 8 * i) * DM + kb + tx] = (__bf16)tile[tx][ty + 8 * i];
}

// ---------------------------------------------------------------------------
// Generic 128x128 bf16-MFMA GEMM:  Out[m][n] = A[m][k] * W[k][n] + bias[n]
// A: [8192][512] fp32 (converted on stage) or bf16.  Bt: [n][k] bf16.
// ---------------------------------------------------------------------------
struct Ptr3 { const void* A; const __bf16* Bt; const float* bias; void* Out; };
struct GemmArgs { Ptr3 p[3]; };

template <bool A_FP32, bool OUT_BF16>
__global__ __launch_bounds__(256) void gemm_tile(GemmArgs args) {
    __shared__ __bf16 Al[128][72];   // stride 144B: 16B-aligned, 2-way banks
    __shared__ __bf16 Bl[128][72];
    const Ptr3 P = args.p[blockIdx.z];
    const int tid = threadIdx.x;
    const int lane = tid & 63, wid = tid >> 6;
    const int lq = lane & 15, hi = lane >> 4;
    const int m0 = blockIdx.x * 128, n0 = blockIdx.y * 128;
    const int wm = (wid >> 1) * 64, wn = (wid & 1) * 64;

    f32x4 acc[4][4] = {};

    for (int kt = 0; kt < DM / 64; ++kt) {
        const int k0 = kt * 64;
        bf16x8 abuf[4], bbuf[4];
        // --- issue global loads (next tile) ---
        if (A_FP32) {
            const float* A = (const float*)P.A;
#pragma unroll
            for (int i = 0; i < 4; ++i) {
                int c = tid + 256 * i, row = c >> 3, cc = c & 7;
                const f32x4* src = (const f32x4*)&A[(size_t)(m0 + row) * DM + k0 + cc * 8];
                f32x4 f0 = src[0], f1 = src[1];
                bf16x8 v;
                v[0] = (__bf16)f0[0]; v[1] = (__bf16)f0[1]; v[2] = (__bf16)f0[2]; v[3] = (__bf16)f0[3];
                v[4] = (__bf16)f1[0]; v[5] = (__bf16)f1[1]; v[6] = (__bf16)f1[2]; v[7] = (__bf16)f1[3];
                abuf[i] = v;
            }
        } else {
            const __bf16* A = (const __bf16*)P.A;
#pragma unroll
            for (int i = 0; i < 4; ++i) {
                int c = tid + 256 * i, row = c >> 3, cc = c & 7;
                abuf[i] = *(const bf16x8*)&A[(size_t)(m0 + row) * DM + k0 + cc * 8];
            }
        }
        {
            const __bf16* Bt = P.Bt;
#pragma unroll
            for (int i = 0; i < 4; ++i) {
                int c = tid + 256 * i, row = c >> 3, cc = c & 7;
                bbuf[i] = *(const bf16x8*)&Bt[(size_t)(n0 + row) * DM + k0 + cc * 8];
            }
        }
        if (kt) __syncthreads();        // prev compute done before overwrite
#pragma unroll
        for (int i = 0; i < 4; ++i) {
            int c = tid + 256 * i, row = c >> 3, cc = c & 7;
            *(bf16x8*)&Al[row][cc * 8] = abuf[i];
            *(bf16x8*)&Bl[row][cc * 8] = bbuf[i];
        }
        __syncthreads();
        // --- compute: 2 K-steps x 16 MFMA ---
#pragma unroll
        for (int ks = 0; ks < 2; ++ks) {
            bf16x8 af[4], bfv[4];
#pragma unroll
            for (int i = 0; i < 4; ++i)
                af[i] = *(const bf16x8*)&Al[wm + i * 16 + lq][ks * 32 + hi * 8];
#pragma unroll
            for (int j = 0; j < 4; ++j)
                bfv[j] = *(const bf16x8*)&Bl[wn + j * 16 + lq][ks * 32 + hi * 8];
#pragma unroll
            for (int i = 0; i < 4; ++i)
#pragma unroll
                for (int j = 0; j < 4; ++j)
                    acc[i][j] = mfma16(af[i], bfv[j], acc[i][j]);
        }
    }
    // --- epilogue ---
    const float* bias = P.bias;
#pragma unroll
    for (int j = 0; j < 4; ++j) {
        const int n = n0 + wn + j * 16 + lq;
        const float bv = bias[n];
#pragma unroll
        for (int i = 0; i < 4; ++i) {
#pragma unroll
            for (int r = 0; r < 4; ++r) {
                const int m = m0 + wm + i * 16 + hi * 4 + r;
                const float v = acc[i][j][r] + bv;
                if (OUT_BF16) ((__bf16*)P.Out)[(size_t)m * DM + n] = (__bf16)v;
                else          ((float*)P.Out)[(size_t)m * DM + n] = v;
            }
        }
    }
}

// ---------------------------------------------------------------------------
// Vp [b*S][512] bf16 -> Vt [bh][dk=64][S] bf16  (per-head transpose)
// ---------------------------------------------------------------------------
__global__ __launch_bounds__(256) void v_transpose(const __bf16* __restrict__ Vp,
                                                   __bf16* __restrict__ Vt) {
    __shared__ __bf16 tile[64][72];
    const int tid = threadIdx.x;
    const int tt = blockIdx.x * 64;
    const int bh = blockIdx.y, b = bh >> 3, h = bh & 7;
#pragma unroll
    for (int i = 0; i < 2; ++i) {
        int c = tid + 256 * i, row = c >> 3, cc = c & 7;   // row = token
        *(bf16x8*)&tile[row][cc * 8] =
            *(const bf16x8*)&Vp[(size_t)(b * SEQ + tt + row) * DM + h * DKH + cc * 8];
    }
    __syncthreads();
#pragma unroll
    for (int i = 0; i < 2; ++i) {
        int c = tid + 256 * i, row = c >> 3, cc = c & 7;   // row = dk
        bf16x8 v;
#pragma unroll
        for (int j = 0; j < 8; ++j) v[j] = tile[cc * 8 + j][row];
        *(bf16x8*)&Vt[(size_t)(bh * DKH + row) * SEQ + tt + cc * 8] = v;
    }
}

// ---------------------------------------------------------------------------
// Flash attention. Block = 4 waves, 64 q-rows (16/wave), KVBLK = 64.
// Swapped QK^T: St[kv][q] = mfma(Kfrag, Qfrag) -> lane owns q-row (lane&15).
// ---------------------------------------------------------------------------
__global__ __launch_bounds__(256) void flash_attn(const __bf16* __restrict__ Qp,
                                                  const __bf16* __restrict__ Kp,
                                                  const __bf16* __restrict__ Vt,
                                                  __bf16* __restrict__ Ctx) {
    __shared__ __bf16 Kl[64][72];
    __shared__ __bf16 Vl[64][72];
    __shared__ __bf16 Pl[4][16][72];
    const int tid = threadIdx.x;
    const int lane = tid & 63, w = tid >> 6;
    const int lq = lane & 15, hi = lane >> 4;
    const int qt = blockIdx.x, bh = blockIdx.y, b = bh >> 3, h = bh & 7;
    const int qrow = qt * 64 + w * 16 + lq;

    // Q fragments (B operand): col q = lane&15, k = ks*32 + hi*8 + j
    bf16x8 qf[2];
#pragma unroll
    for (int ks = 0; ks < 2; ++ks)
        qf[ks] = *(const bf16x8*)&Qp[(size_t)(b * SEQ + qrow) * DM + h * DKH + ks * 32 + hi * 8];

    f32x4 acc[4] = {};                 // ctx accum: nt over dk, rows q=hi*4+r
    float m_run = -__builtin_inff(), l_run = 0.f;

    for (int kvt = 0; kvt < SEQ / 64; ++kvt) {
        const int kv0 = kvt * 64;
        bf16x8 kbuf[2], vbuf[2];
#pragma unroll
        for (int i = 0; i < 2; ++i) {
            int c = tid + 256 * i, row = c >> 3, cc = c & 7;
            kbuf[i] = *(const bf16x8*)&Kp[(size_t)(b * SEQ + kv0 + row) * DM + h * DKH + cc * 8];
            vbuf[i] = *(const bf16x8*)&Vt[(size_t)(bh * DKH + row) * SEQ + kv0 + cc * 8];
        }
        if (kvt) __syncthreads();
#pragma unroll
        for (int i = 0; i < 2; ++i) {
            int c = tid + 256 * i, row = c >> 3, cc = c & 7;
            *(bf16x8*)&Kl[row][cc * 8] = kbuf[i];
            *(bf16x8*)&Vl[row][cc * 8] = vbuf[i];
        }
        __syncthreads();

        // QK^T (swapped): s[mt] rows kv = mt*16 + hi*4 + r, col q = lq
        f32x4 s[4] = {};
#pragma unroll
        for (int ks = 0; ks < 2; ++ks) {
#pragma unroll
            for (int mt = 0; mt < 4; ++mt) {
                bf16x8 kf = *(const bf16x8*)&Kl[mt * 16 + lq][ks * 32 + hi * 8];
                s[mt] = mfma16(kf, qf[ks], s[mt]);
            }
        }

        // online softmax for q-row lq (4 lanes share it; reduce over hi)
        float mx = m_run;
        float sc[4][4];
#pragma unroll
        for (int mt = 0; mt < 4; ++mt)
#pragma unroll
            for (int r = 0; r < 4; ++r) {
                float v = s[mt][r] * 0.125f;   // 1/sqrt(64)
                sc[mt][r] = v;
                mx = fmaxf(mx, v);
            }
        mx = fmaxf(mx, __shfl_xor(mx, 16));
        mx = fmaxf(mx, __shfl_xor(mx, 32));
        const float alpha = __expf(m_run - mx);
        m_run = mx;
        float lsum = 0.f;
#pragma unroll
        for (int mt = 0; mt < 4; ++mt) {
            bf16x4 pb;
#pragma unroll
            for (int r = 0; r < 4; ++r) {
                float p = __expf(sc[mt][r] - mx);
                lsum += p;
                pb[r] = (__bf16)p;
            }
            *(bf16x4*)&Pl[w][lq][mt * 16 + hi * 4] = pb;   // wave-local, in-order DS
        }
        lsum += __shfl_xor(lsum, 16);
        lsum += __shfl_xor(lsum, 32);
        l_run = l_run * alpha + lsum;

        // rescale ctx accumulator rows (q = hi*4 + r)
        float ar[4];
#pragma unroll
        for (int r = 0; r < 4; ++r) ar[r] = __shfl(alpha, hi * 4 + r);
#pragma unroll
        for (int nt = 0; nt < 4; ++nt)
#pragma unroll
            for (int r = 0; r < 4; ++r) acc[nt][r] *= ar[r];

        // PV: ctx[q][dk] += P[q][kv] * V[kv][dk]
#pragma unroll
        for (int ks = 0; ks < 2; ++ks) {
            bf16x8 pf = *(const bf16x8*)&Pl[w][lq][ks * 32 + hi * 8];
#pragma unroll
            for (int nt = 0; nt < 4; ++nt) {
                bf16x8 vf = *(const bf16x8*)&Vl[nt * 16 + lq][ks * 32 + hi * 8];
                acc[nt] = mfma16(pf, vf, acc[nt]);
            }
        }
    }

    // epilogue: divide by l, store bf16 ctx
    float lr[4];
#pragma unroll
    for (int r = 0; r < 4; ++r) lr[r] = __shfl(l_run, hi * 4 + r);
#pragma unroll
    for (int nt = 0; nt < 4; ++nt)
#pragma unroll
        for (int r = 0; r < 4; ++r) {
            const int m = qt * 64 + w * 16 + hi * 4 + r;
            const float o = acc[nt][r] / lr[r];
            Ctx[(size_t)(b * SEQ + m) * DM + h * DKH + nt * 16 + lq] = (__bf16)o;
        }
}

// ---------------------------------------------------------------------------
extern "C" void kernel_launch(void* const* d_in, const int* in_sizes, int n_in,
                              void* d_out, int out_size, void* d_ws, size_t ws_size,
                              hipStream_t stream) {
    (void)in_sizes; (void)n_in; (void)out_size;
    const float* query = (const float*)d_in[0];
    const float* key_  = (const float*)d_in[1];
    const float* value = (const float*)d_in[2];
    const float* Wq = (const float*)d_in[3];
    const float* bq = (const float*)d_in[4];
    const float* Wk = (const float*)d_in[5];
    const float* bk = (const float*)d_in[6];
    const float* Wv = (const float*)d_in[7];
    const float* bv = (const float*)d_in[8];
    const float* Wo = (const float*)d_in[9];
    const float* bo = (const float*)d_in[10];

    char* ws = (char*)d_ws;
    const size_t WSZ = (size_t)512 * 1024;        // 512KB per transposed weight
    const size_t XSZ = (size_t)8 * 1024 * 1024;   // 8MB per activation buffer
    if (ws_size < 4 * WSZ + 5 * XSZ) return;      // need 42MB scratch
    __bf16* Wtq = (__bf16*)(ws);
    __bf16* Wtk = (__bf16*)(ws + WSZ);
    __bf16* Wtv = (__bf16*)(ws + 2 * WSZ);
    __bf16* Wto = (__bf16*)(ws + 3 * WSZ);
    char* xb = ws + 4 * WSZ;
    __bf16* Qp  = (__bf16*)(xb);
    __bf16* Kp  = (__bf16*)(xb + XSZ);
    __bf16* Vp  = (__bf16*)(xb + 2 * XSZ);
    __bf16* Vt  = (__bf16*)(xb + 3 * XSZ);
    __bf16* Ctx = (__bf16*)(xb + 4 * XSZ);

    wt_convert<<<dim3(16, 16), 256, 0, stream>>>(Wq, Wtq);
    wt_convert<<<dim3(16, 16), 256, 0, stream>>>(Wk, Wtk);
    wt_convert<<<dim3(16, 16), 256, 0, stream>>>(Wv, Wtv);
    wt_convert<<<dim3(16, 16), 256, 0, stream>>>(Wo, Wto);

    GemmArgs qa;
    qa.p[0] = {query, Wtq, bq, Qp};
    qa.p[1] = {key_,  Wtk, bk, Kp};
    qa.p[2] = {value, Wtv, bv, Vp};
    gemm_tile<true, true><<<dim3(64, 4, 3), 256, 0, stream>>>(qa);

    v_transpose<<<dim3(SEQ / 64, BATCH * HEADS), 256, 0, stream>>>(Vp, Vt);

    flash_attn<<<dim3(SEQ / 64, BATCH * HEADS), 256, 0, stream>>>(Qp, Kp, Vt, Ctx);

    GemmArgs oa;
    oa.p[0] = {Ctx, Wto, bo, d_out};
    oa.p[1] = oa.p[0]; oa.p[2] = oa.p[0];
    gemm_tile<false, false><<<dim3(64, 4, 1), 256, 0, stream>>>(oa);
}

// Round 2
// 255.532 us; speedup vs baseline: 1.1922x; 1.1922x over previous
//
#include <hip/hip_runtime.h>
#include <hip/hip_bf16.h>

#define DM   512
#define HEADS 8
#define DKH  64
#define BATCH 2
#define SEQ  4096

typedef float  f32x4  __attribute__((ext_vector_type(4)));
typedef float  f32x16 __attribute__((ext_vector_type(16)));
typedef __bf16 bf16x8 __attribute__((ext_vector_type(8)));
typedef __bf16 bf16x4 __attribute__((ext_vector_type(4)));
typedef __bf16 bf16x2 __attribute__((ext_vector_type(2)));

static __device__ __forceinline__ f32x4 mfma16(bf16x8 a, bf16x8 b, f32x4 c) {
    return __builtin_amdgcn_mfma_f32_16x16x32_bf16(a, b, c, 0, 0, 0);
}
static __device__ __forceinline__ f32x16 mfma32(bf16x8 a, bf16x8 b, f32x16 c) {
    return __builtin_amdgcn_mfma_f32_32x32x16_bf16(a, b, c, 0, 0, 0);
}

// async global->LDS, 16B per lane; LDS dest = wave-uniform base + lane*16
#define GLD16(gp, lp) __builtin_amdgcn_global_load_lds( \
    (const __attribute__((address_space(1))) void*)(gp), \
    (__attribute__((address_space(3))) void*)(lp), 16, 0, 0)

// ---------------------------------------------------------------------------
// All four W [k][n] fp32 -> Wt [n][k] bf16 in one launch (z = weight index)
// ---------------------------------------------------------------------------
struct WtAll { const float* W[4]; __bf16* Wt[4]; };

__global__ __launch_bounds__(256) void wt_convert_all(WtAll a) {
    const float* W = a.W[blockIdx.z];
    __bf16* Wt = a.Wt[blockIdx.z];
    __shared__ float tile[32][33];
    const int tx = threadIdx.x & 31, ty = threadIdx.x >> 5;  // ty 0..7
    const int nb = blockIdx.x * 32, kb = blockIdx.y * 32;
#pragma unroll
    for (int i = 0; i < 4; ++i)
        tile[ty + 8 * i][tx] = W[(size_t)(kb + ty + 8 * i) * DM + nb + tx];
    __syncthreads();
#pragma unroll
    for (int i = 0; i < 4; ++i)
        Wt[(size_t)(nb + ty + 8 * i) * DM + kb + tx] = (__bf16)tile[tx][ty + 8 * i];
}

// ---------------------------------------------------------------------------
// Generic 128x128 bf16-MFMA GEMM:  Out[m][n] = (A[m][k] * W[k][n] + bias[n])*s
// ---------------------------------------------------------------------------
struct Ptr3 { const void* A; const __bf16* Bt; const float* bias; void* Out; float ascale; };
struct GemmArgs { Ptr3 p[3]; };

template <bool A_FP32, bool OUT_BF16>
__global__ __launch_bounds__(256) void gemm_tile(GemmArgs args) {
    __shared__ __bf16 Al[128][72];
    __shared__ __bf16 Bl[128][72];
    const Ptr3 P = args.p[blockIdx.z];
    const int tid = threadIdx.x;
    const int lane = tid & 63, wid = tid >> 6;
    const int lq = lane & 15, hi = lane >> 4;
    const int m0 = blockIdx.x * 128, n0 = blockIdx.y * 128;
    const int wm = (wid >> 1) * 64, wn = (wid & 1) * 64;

    f32x4 acc[4][4] = {};

    for (int kt = 0; kt < DM / 64; ++kt) {
        const int k0 = kt * 64;
        bf16x8 abuf[4], bbuf[4];
        if (A_FP32) {
            const float* A = (const float*)P.A;
#pragma unroll
            for (int i = 0; i < 4; ++i) {
                int c = tid + 256 * i, row = c >> 3, cc = c & 7;
                const f32x4* src = (const f32x4*)&A[(size_t)(m0 + row) * DM + k0 + cc * 8];
                f32x4 f0 = src[0], f1 = src[1];
                bf16x8 v;
                v[0] = (__bf16)f0[0]; v[1] = (__bf16)f0[1]; v[2] = (__bf16)f0[2]; v[3] = (__bf16)f0[3];
                v[4] = (__bf16)f1[0]; v[5] = (__bf16)f1[1]; v[6] = (__bf16)f1[2]; v[7] = (__bf16)f1[3];
                abuf[i] = v;
            }
        } else {
            const __bf16* A = (const __bf16*)P.A;
#pragma unroll
            for (int i = 0; i < 4; ++i) {
                int c = tid + 256 * i, row = c >> 3, cc = c & 7;
                abuf[i] = *(const bf16x8*)&A[(size_t)(m0 + row) * DM + k0 + cc * 8];
            }
        }
        {
            const __bf16* Bt = P.Bt;
#pragma unroll
            for (int i = 0; i < 4; ++i) {
                int c = tid + 256 * i, row = c >> 3, cc = c & 7;
                bbuf[i] = *(const bf16x8*)&Bt[(size_t)(n0 + row) * DM + k0 + cc * 8];
            }
        }
        if (kt) __syncthreads();
#pragma unroll
        for (int i = 0; i < 4; ++i) {
            int c = tid + 256 * i, row = c >> 3, cc = c & 7;
            *(bf16x8*)&Al[row][cc * 8] = abuf[i];
            *(bf16x8*)&Bl[row][cc * 8] = bbuf[i];
        }
        __syncthreads();
#pragma unroll
        for (int ks = 0; ks < 2; ++ks) {
            bf16x8 af[4], bfv[4];
#pragma unroll
            for (int i = 0; i < 4; ++i)
                af[i] = *(const bf16x8*)&Al[wm + i * 16 + lq][ks * 32 + hi * 8];
#pragma unroll
            for (int j = 0; j < 4; ++j)
                bfv[j] = *(const bf16x8*)&Bl[wn + j * 16 + lq][ks * 32 + hi * 8];
#pragma unroll
            for (int i = 0; i < 4; ++i)
#pragma unroll
                for (int j = 0; j < 4; ++j)
                    acc[i][j] = mfma16(af[i], bfv[j], acc[i][j]);
        }
    }
    const float* bias = P.bias;
    const float asc = P.ascale;
#pragma unroll
    for (int j = 0; j < 4; ++j) {
        const int n = n0 + wn + j * 16 + lq;
        const float bv = bias[n];
#pragma unroll
        for (int i = 0; i < 4; ++i) {
#pragma unroll
            for (int r = 0; r < 4; ++r) {
                const int m = m0 + wm + i * 16 + hi * 4 + r;
                const float v = (acc[i][j][r] + bv) * asc;
                if (OUT_BF16) ((__bf16*)P.Out)[(size_t)m * DM + n] = (__bf16)v;
                else          ((float*)P.Out)[(size_t)m * DM + n] = v;
            }
        }
    }
}

// ---------------------------------------------------------------------------
// Vp [b*S][512] bf16 -> Vt [bh][dk=64][S] bf16  (per-head transpose)
// ---------------------------------------------------------------------------
__global__ __launch_bounds__(256) void v_transpose(const __bf16* __restrict__ Vp,
                                                   __bf16* __restrict__ Vt) {
    __shared__ __bf16 tile[64][72];
    const int tid = threadIdx.x;
    const int tt = blockIdx.x * 64;
    const int bh = blockIdx.y, b = bh >> 3, h = bh & 7;
#pragma unroll
    for (int i = 0; i < 2; ++i) {
        int c = tid + 256 * i, row = c >> 3, cc = c & 7;
        *(bf16x8*)&tile[row][cc * 8] =
            *(const bf16x8*)&Vp[(size_t)(b * SEQ + tt + row) * DM + h * DKH + cc * 8];
    }
    __syncthreads();
#pragma unroll
    for (int i = 0; i < 2; ++i) {
        int c = tid + 256 * i, row = c >> 3, cc = c & 7;
        bf16x8 v;
#pragma unroll
        for (int j = 0; j < 8; ++j) v[j] = tile[cc * 8 + j][row];
        *(bf16x8*)&Vt[(size_t)(bh * DKH + row) * SEQ + tt + cc * 8] = v;
    }
}

// ---------------------------------------------------------------------------
// Flash attention, 32x32x16 MFMA. Block = 4 waves x 32 q-rows = 128 q.
// Swapped QK^T: S[kv][q] = mfma(K, Q) -> lane owns q-column c = lane&31,
// holds 16 of 32 kv per subtile (partner lane c+32 holds the rest).
// Q pre-scaled by 0.125*log2(e) -> softmax in exp2 domain.
// P kept in registers; PV A-frag built with one lane<->lane+32 exchange.
// K/V staged via global_load_lds with XOR-swizzled source; double-buffered.
// ---------------------------------------------------------------------------
__global__ __launch_bounds__(256) void flash_attn2(const __bf16* __restrict__ Qp,
                                                   const __bf16* __restrict__ Kp,
                                                   const __bf16* __restrict__ Vt,
                                                   __bf16* __restrict__ Ctx) {
    __shared__ __bf16 Kl[2][64][64];   // 16 KB, swizzled: slot ^= (row^(row>>3))&7
    __shared__ __bf16 Vl[2][64][64];   // 16 KB
    __shared__ float  Lbuf[4][32];     // per-wave q-column broadcast

    const int tid = threadIdx.x, lane = tid & 63, w = tid >> 6;
    const int c = lane & 31, h = lane >> 5;
    const int bh = blockIdx.y, b = bh >> 3, hd = bh & 7;
    const int qbase = blockIdx.x * 128 + w * 32;

    // Q fragments (B-operand): col=q=c, k = 16t + 8h + j
    bf16x8 qf[4];
#pragma unroll
    for (int t = 0; t < 4; ++t)
        qf[t] = *(const bf16x8*)&Qp[(size_t)(b * SEQ + qbase + c) * DM + hd * DKH + 16 * t + 8 * h];

    // staging: wave w covers rows [w*16, w*16+16) of K and V tiles
    const int r0 = w * 16 + (lane >> 3);
    const int r1 = r0 + 8;
    const int s0 = (lane & 7) ^ ((r0 ^ (r0 >> 3)) & 7);
    const int s1 = (lane & 7) ^ ((r1 ^ (r1 >> 3)) & 7);
    const __bf16* kg0 = Kp + (size_t)(b * SEQ + r0) * DM + hd * DKH + s0 * 8;
    const __bf16* kg1 = Kp + (size_t)(b * SEQ + r1) * DM + hd * DKH + s1 * 8;
    const __bf16* vg0 = Vt + (size_t)(bh * DKH + r0) * SEQ + s0 * 8;
    const __bf16* vg1 = Vt + (size_t)(bh * DKH + r1) * SEQ + s1 * 8;

    // read-side swizzles (rows c and 32+c)
    const int swz0 = (c ^ (c >> 3)) & 7;
    const int swz1 = ((32 + c) ^ ((32 + c) >> 3)) & 7;
    const int rowb0 = c * 128, rowb1 = (32 + c) * 128;
    const char* kb = (const char*)&Kl[0][0][0];
    const char* vb = (const char*)&Vl[0][0][0];

    f32x16 acc0 = {}, acc1 = {};
    float m_run = -__builtin_inff(), l_run = 0.f;

    // prologue: stage tile 0 into buffer 0
    GLD16(kg0, &Kl[0][w * 16][0]);
    GLD16(kg1, &Kl[0][w * 16 + 8][0]);
    GLD16(vg0, &Vl[0][w * 16][0]);
    GLD16(vg1, &Vl[0][w * 16 + 8][0]);
    __syncthreads();   // drains vmcnt(0) before barrier

    const int NT = SEQ / 64;
    for (int kvt = 0; kvt < NT; ++kvt) {
        const int cur = kvt & 1;
        if (kvt + 1 < NT) {                      // prefetch next tile
            const size_t ko = (size_t)(kvt + 1) * 64 * DM;
            const size_t vo = (size_t)(kvt + 1) * 64;
            GLD16(kg0 + ko, &Kl[cur ^ 1][w * 16][0]);
            GLD16(kg1 + ko, &Kl[cur ^ 1][w * 16 + 8][0]);
            GLD16(vg0 + vo, &Vl[cur ^ 1][w * 16][0]);
            GLD16(vg1 + vo, &Vl[cur ^ 1][w * 16 + 8][0]);
        }
        const char* kc = kb + cur * (64 * 128);
        const char* vc = vb + cur * (64 * 128);

        // ---- QK^T: two kv-subtiles of 32
        f32x16 sa = {}, sb = {};
        __builtin_amdgcn_s_setprio(1);
#pragma unroll
        for (int t = 0; t < 4; ++t) {
            bf16x8 kf0 = *(const bf16x8*)(kc + rowb0 + (((2 * t + h) ^ swz0) << 4));
            sa = mfma32(kf0, qf[t], sa);
            bf16x8 kf1 = *(const bf16x8*)(kc + rowb1 + (((2 * t + h) ^ swz1) << 4));
            sb = mfma32(kf1, qf[t], sb);
        }
        __builtin_amdgcn_s_setprio(0);

        // ---- online softmax (exp2 domain), defer-max THR=8
        float mx = sa[0];
#pragma unroll
        for (int r = 1; r < 16; ++r) mx = fmaxf(mx, sa[r]);
#pragma unroll
        for (int r = 0; r < 16; ++r) mx = fmaxf(mx, sb[r]);
        mx = fmaxf(mx, __shfl_xor(mx, 32));
        if (!__all(mx <= m_run + 8.f)) {
            const float mnew = fmaxf(m_run, mx);
            const float al = __builtin_amdgcn_exp2f(m_run - mnew);
            m_run = mnew;
            l_run *= al;
            if (lane < 32) Lbuf[w][lane] = al;
#pragma unroll
            for (int r = 0; r < 16; ++r) {
                const float a2 = Lbuf[w][(r & 3) + 8 * (r >> 2) + 4 * h];
                acc0[r] *= a2; acc1[r] *= a2;
            }
        }
        float ls = 0.f;
        float pa[16], pb[16];
#pragma unroll
        for (int r = 0; r < 16; ++r) { pa[r] = __builtin_amdgcn_exp2f(sa[r] - m_run); ls += pa[r]; }
#pragma unroll
        for (int r = 0; r < 16; ++r) { pb[r] = __builtin_amdgcn_exp2f(sb[r] - m_run); ls += pb[r]; }
        ls += __shfl_xor(ls, 32);
        l_run += ls;

        // ---- pack P to bf16 pairs: u[q4][i] holds kv {8q4+4h+2i, +1}
        int ua[4][2], ub[4][2];
#pragma unroll
        for (int q4 = 0; q4 < 4; ++q4)
#pragma unroll
            for (int i = 0; i < 2; ++i) {
                bf16x2 ta; ta[0] = (__bf16)pa[4 * q4 + 2 * i]; ta[1] = (__bf16)pa[4 * q4 + 2 * i + 1];
                ua[q4][i] = __builtin_bit_cast(int, ta);
                bf16x2 tb; tb[0] = (__bf16)pb[4 * q4 + 2 * i]; tb[1] = (__bf16)pb[4 * q4 + 2 * i + 1];
                ub[q4][i] = __builtin_bit_cast(int, tb);
            }

        // ---- PV: A-frag for inst t needs P[q=c][kv=16t+8h+j]; exchange with lane^32
#define EXCH(U, tl, W0, W1, W2, W3) do {                         \
            int z0 = h ? (U)[2*(tl)][0] : (U)[2*(tl)+1][0];      \
            int y0 = __shfl_xor(z0, 32);                         \
            W0 = h ? y0 : (U)[2*(tl)][0];                        \
            W2 = h ? (U)[2*(tl)+1][0] : y0;                      \
            int z1 = h ? (U)[2*(tl)][1] : (U)[2*(tl)+1][1];      \
            int y1 = __shfl_xor(z1, 32);                         \
            W1 = h ? y1 : (U)[2*(tl)][1];                        \
            W3 = h ? (U)[2*(tl)+1][1] : y1; } while (0)

#pragma unroll
        for (int tg = 0; tg < 4; ++tg) {
            int w0, w1, w2, w3;
            if (tg < 2) { EXCH(ua, tg, w0, w1, w2, w3); }
            else        { EXCH(ub, (tg - 2), w0, w1, w2, w3); }
            union { int i4[4]; bf16x8 v; } pf;
            pf.i4[0] = w0; pf.i4[1] = w1; pf.i4[2] = w2; pf.i4[3] = w3;
            bf16x8 vf0 = *(const bf16x8*)(vc + rowb0 + (((2 * tg + h) ^ swz0) << 4));
            bf16x8 vf1 = *(const bf16x8*)(vc + rowb1 + (((2 * tg + h) ^ swz1) << 4));
            __builtin_amdgcn_s_setprio(1);
            acc0 = mfma32(pf.v, vf0, acc0);
            acc1 = mfma32(pf.v, vf1, acc1);
            __builtin_amdgcn_s_setprio(0);
        }
#undef EXCH
        __syncthreads();   // drains this tile's prefetch DMA + all LDS reads
    }

    // ---- epilogue: ctx row q = qmap(r,h), col dk = 32*dkt + c
    if (lane < 32) Lbuf[w][lane] = l_run;
    __bf16* outp = Ctx + (size_t)(b * SEQ + qbase) * DM + hd * DKH;
#pragma unroll
    for (int r = 0; r < 16; ++r) {
        const int qr = (r & 3) + 8 * (r >> 2) + 4 * h;
        const float li = 1.f / Lbuf[w][qr];
        outp[(size_t)qr * DM + c]      = (__bf16)(acc0[r] * li);
        outp[(size_t)qr * DM + 32 + c] = (__bf16)(acc1[r] * li);
    }
}

// ---------------------------------------------------------------------------
extern "C" void kernel_launch(void* const* d_in, const int* in_sizes, int n_in,
                              void* d_out, int out_size, void* d_ws, size_t ws_size,
                              hipStream_t stream) {
    (void)in_sizes; (void)n_in; (void)out_size;
    const float* query = (const float*)d_in[0];
    const float* key_  = (const float*)d_in[1];
    const float* value = (const float*)d_in[2];
    const float* Wq = (const float*)d_in[3];
    const float* bq = (const float*)d_in[4];
    const float* Wk = (const float*)d_in[5];
    const float* bk = (const float*)d_in[6];
    const float* Wv = (const float*)d_in[7];
    const float* bv = (const float*)d_in[8];
    const float* Wo = (const float*)d_in[9];
    const float* bo = (const float*)d_in[10];

    char* ws = (char*)d_ws;
    const size_t WSZ = (size_t)512 * 1024;
    const size_t XSZ = (size_t)8 * 1024 * 1024;
    if (ws_size < 4 * WSZ + 5 * XSZ) return;
    __bf16* Wtq = (__bf16*)(ws);
    __bf16* Wtk = (__bf16*)(ws + WSZ);
    __bf16* Wtv = (__bf16*)(ws + 2 * WSZ);
    __bf16* Wto = (__bf16*)(ws + 3 * WSZ);
    char* xb = ws + 4 * WSZ;
    __bf16* Qp  = (__bf16*)(xb);
    __bf16* Kp  = (__bf16*)(xb + XSZ);
    __bf16* Vp  = (__bf16*)(xb + 2 * XSZ);
    __bf16* Vt  = (__bf16*)(xb + 3 * XSZ);
    __bf16* Ctx = (__bf16*)(xb + 4 * XSZ);

    WtAll wa;
    wa.W[0] = Wq; wa.W[1] = Wk; wa.W[2] = Wv; wa.W[3] = Wo;
    wa.Wt[0] = Wtq; wa.Wt[1] = Wtk; wa.Wt[2] = Wtv; wa.Wt[3] = Wto;
    wt_convert_all<<<dim3(16, 16, 4), 256, 0, stream>>>(wa);

    // Q projection folds in 1/sqrt(dk) * log2(e) so softmax runs in exp2 domain
    const float QSC = 0.125f * 1.4426950408889634f;
    GemmArgs qa;
    qa.p[0] = {query, Wtq, bq, Qp, QSC};
    qa.p[1] = {key_,  Wtk, bk, Kp, 1.0f};
    qa.p[2] = {value, Wtv, bv, Vp, 1.0f};
    gemm_tile<true, true><<<dim3(64, 4, 3), 256, 0, stream>>>(qa);

    v_transpose<<<dim3(SEQ / 64, BATCH * HEADS), 256, 0, stream>>>(Vp, Vt);

    flash_attn2<<<dim3(SEQ / 128, BATCH * HEADS), 256, 0, stream>>>(Qp, Kp, Vt, Ctx);

    GemmArgs oa;
    oa.p[0] = {Ctx, Wto, bo, d_out, 1.0f};
    oa.p[1] = oa.p[0]; oa.p[2] = oa.p[0];
    gemm_tile<false, false><<<dim3(64, 4, 1), 256, 0, stream>>>(oa);
}

// Round 3
// 251.426 us; speedup vs baseline: 1.2116x; 1.0163x over previous
//
#include <hip/hip_runtime.h>
#include <hip/hip_bf16.h>

#define DM   512
#define HEADS 8
#define DKH  64
#define BATCH 2
#define SEQ  4096

typedef float  f32x4  __attribute__((ext_vector_type(4)));
typedef float  f32x16 __attribute__((ext_vector_type(16)));
typedef __bf16 bf16x8 __attribute__((ext_vector_type(8)));
typedef __bf16 bf16x4 __attribute__((ext_vector_type(4)));
typedef __bf16 bf16x2 __attribute__((ext_vector_type(2)));

static __device__ __forceinline__ f32x4 mfma16(bf16x8 a, bf16x8 b, f32x4 c) {
    return __builtin_amdgcn_mfma_f32_16x16x32_bf16(a, b, c, 0, 0, 0);
}
static __device__ __forceinline__ f32x16 mfma32(bf16x8 a, bf16x8 b, f32x16 c) {
    return __builtin_amdgcn_mfma_f32_32x32x16_bf16(a, b, c, 0, 0, 0);
}

// async global->LDS, 16B per lane; LDS dest = wave-uniform base + lane*16
#define GLD16(gp, lp) __builtin_amdgcn_global_load_lds( \
    (const __attribute__((address_space(1))) void*)(gp), \
    (__attribute__((address_space(3))) void*)(lp), 16, 0, 0)

// ---------------------------------------------------------------------------
// fp32 -> bf16 elementwise, 3 tensors (blockIdx.y selects), 8 elems/thread
// ---------------------------------------------------------------------------
struct Cvt3 { const float* s[3]; __bf16* d[3]; };

__global__ __launch_bounds__(256) void convert_x3(Cvt3 a) {
    const float* s = a.s[blockIdx.y];
    __bf16* d = a.d[blockIdx.y];
    const size_t i = ((size_t)blockIdx.x * 256 + threadIdx.x) * 8;
    f32x4 f0 = *(const f32x4*)&s[i];
    f32x4 f1 = *(const f32x4*)&s[i + 4];
    bf16x8 v;
    v[0] = (__bf16)f0[0]; v[1] = (__bf16)f0[1]; v[2] = (__bf16)f0[2]; v[3] = (__bf16)f0[3];
    v[4] = (__bf16)f1[0]; v[5] = (__bf16)f1[1]; v[6] = (__bf16)f1[2]; v[7] = (__bf16)f1[3];
    *(bf16x8*)&d[i] = v;
}

// ---------------------------------------------------------------------------
// All four W [k][n] fp32 -> Wt [n][k] bf16 in one launch (z = weight index)
// ---------------------------------------------------------------------------
struct WtAll { const float* W[4]; __bf16* Wt[4]; };

__global__ __launch_bounds__(256) void wt_convert_all(WtAll a) {
    const float* W = a.W[blockIdx.z];
    __bf16* Wt = a.Wt[blockIdx.z];
    __shared__ float tile[32][33];
    const int tx = threadIdx.x & 31, ty = threadIdx.x >> 5;
    const int nb = blockIdx.x * 32, kb = blockIdx.y * 32;
#pragma unroll
    for (int i = 0; i < 4; ++i)
        tile[ty + 8 * i][tx] = W[(size_t)(kb + ty + 8 * i) * DM + nb + tx];
    __syncthreads();
#pragma unroll
    for (int i = 0; i < 4; ++i)
        Wt[(size_t)(nb + ty + 8 * i) * DM + kb + tx] = (__bf16)tile[tx][ty + 8 * i];
}

// ---------------------------------------------------------------------------
// 128x128 bf16-MFMA GEMM, m97 structure: global_load_lds staging (bf16 A path)
// Out[m][n] = (A[m][k] * W[k][n] + bias[n]) * ascale
// ---------------------------------------------------------------------------
struct Ptr3 { const void* A; const __bf16* Bt; const float* bias; void* Out; float ascale; };
struct GemmArgs { Ptr3 p[3]; };

template <bool A_FP32, bool OUT_BF16>
__global__ __launch_bounds__(256) void gemm_tile(GemmArgs args) {
    __shared__ __bf16 Al[128][64];   // 16 KB, linear (GLD16 dest)
    __shared__ __bf16 Bl[128][64];
    const Ptr3 P = args.p[blockIdx.z];
    const int tid = threadIdx.x;
    const int lane = tid & 63, wid = tid >> 6;
    const int lq = lane & 15, hi = lane >> 4;
    const int m0 = blockIdx.x * 128, n0 = blockIdx.y * 128;
    const int wm = (wid >> 1) * 64, wn = (wid & 1) * 64;

    // staging geometry: wave covers rows [wid*32, wid*32+32), 4 issues of 8 rows
    const int srow = wid * 32 + (lane >> 3);
    const int scol = (lane & 7) * 8;
    const __bf16* gb = P.Bt + (size_t)(n0 + srow) * DM + scol;
    const __bf16* ga = (const __bf16*)P.A + (size_t)(m0 + srow) * DM + scol;

    f32x4 acc[4][4] = {};

    for (int kt = 0; kt < DM / 64; ++kt) {
        const int k0 = kt * 64;
        if (kt) __syncthreads();            // readers of prev tile done
        if (A_FP32) {
            const float* A = (const float*)P.A;
            bf16x8 abuf[4];
#pragma unroll
            for (int i = 0; i < 4; ++i) {
                int cc = tid + 256 * i, row = cc >> 3, col = cc & 7;
                const f32x4* src = (const f32x4*)&A[(size_t)(m0 + row) * DM + k0 + col * 8];
                f32x4 f0 = src[0], f1 = src[1];
                bf16x8 v;
                v[0] = (__bf16)f0[0]; v[1] = (__bf16)f0[1]; v[2] = (__bf16)f0[2]; v[3] = (__bf16)f0[3];
                v[4] = (__bf16)f1[0]; v[5] = (__bf16)f1[1]; v[6] = (__bf16)f1[2]; v[7] = (__bf16)f1[3];
                abuf[i] = v;
            }
#pragma unroll
            for (int i = 0; i < 4; ++i) {
                int cc = tid + 256 * i, row = cc >> 3, col = cc & 7;
                *(bf16x8*)&Al[row][col * 8] = abuf[i];
            }
        } else {
#pragma unroll
            for (int i = 0; i < 4; ++i)
                GLD16(ga + k0 + (size_t)i * 8 * DM, &Al[wid * 32 + i * 8][0]);
        }
#pragma unroll
        for (int i = 0; i < 4; ++i)
            GLD16(gb + k0 + (size_t)i * 8 * DM, &Bl[wid * 32 + i * 8][0]);
        __syncthreads();                    // drains DMA (vmcnt) + ds_writes

        __builtin_amdgcn_s_setprio(1);
#pragma unroll
        for (int ks = 0; ks < 2; ++ks) {
            bf16x8 af[4], bfv[4];
#pragma unroll
            for (int i = 0; i < 4; ++i)
                af[i] = *(const bf16x8*)&Al[wm + i * 16 + lq][ks * 32 + hi * 8];
#pragma unroll
            for (int j = 0; j < 4; ++j)
                bfv[j] = *(const bf16x8*)&Bl[wn + j * 16 + lq][ks * 32 + hi * 8];
#pragma unroll
            for (int i = 0; i < 4; ++i)
#pragma unroll
                for (int j = 0; j < 4; ++j)
                    acc[i][j] = mfma16(af[i], bfv[j], acc[i][j]);
        }
        __builtin_amdgcn_s_setprio(0);
    }
    const float* bias = P.bias;
    const float asc = P.ascale;
#pragma unroll
    for (int j = 0; j < 4; ++j) {
        const int n = n0 + wn + j * 16 + lq;
        const float bv = bias[n];
#pragma unroll
        for (int i = 0; i < 4; ++i) {
#pragma unroll
            for (int r = 0; r < 4; ++r) {
                const int m = m0 + wm + i * 16 + hi * 4 + r;
                const float v = (acc[i][j][r] + bv) * asc;
                if (OUT_BF16) ((__bf16*)P.Out)[(size_t)m * DM + n] = (__bf16)v;
                else          ((float*)P.Out)[(size_t)m * DM + n] = v;
            }
        }
    }
}

// ---------------------------------------------------------------------------
// Vp [b*S][512] bf16 -> Vt [bh][dk=64][S] bf16  (per-head transpose)
// ---------------------------------------------------------------------------
__global__ __launch_bounds__(256) void v_transpose(const __bf16* __restrict__ Vp,
                                                   __bf16* __restrict__ Vt) {
    __shared__ __bf16 tile[64][72];
    const int tid = threadIdx.x;
    const int tt = blockIdx.x * 64;
    const int bh = blockIdx.y, b = bh >> 3, h = bh & 7;
#pragma unroll
    for (int i = 0; i < 2; ++i) {
        int c = tid + 256 * i, row = c >> 3, cc = c & 7;
        *(bf16x8*)&tile[row][cc * 8] =
            *(const bf16x8*)&Vp[(size_t)(b * SEQ + tt + row) * DM + h * DKH + cc * 8];
    }
    __syncthreads();
#pragma unroll
    for (int i = 0; i < 2; ++i) {
        int c = tid + 256 * i, row = c >> 3, cc = c & 7;
        bf16x8 v;
#pragma unroll
        for (int j = 0; j < 8; ++j) v[j] = tile[cc * 8 + j][row];
        *(bf16x8*)&Vt[(size_t)(bh * DKH + row) * SEQ + tt + cc * 8] = v;
    }
}

// ---------------------------------------------------------------------------
// Flash attention, 32x32x16 MFMA, 4 waves x 32 q = 128 q per block.
// SPLIT: blockIdx.z = kv-half; writes bf16 partial ctx + (m,l) per q-row.
// PV A-frag relayout via v_permlane32_swap_b32 (replaces shfl+cndmask chain).
// ---------------------------------------------------------------------------
template <bool SPLIT>
__global__ __launch_bounds__(256, 4) void flash_attn3(const __bf16* __restrict__ Qp,
                                                      const __bf16* __restrict__ Kp,
                                                      const __bf16* __restrict__ Vt,
                                                      __bf16* __restrict__ O0,
                                                      __bf16* __restrict__ O1,
                                                      float2* __restrict__ ml) {
    __shared__ __bf16 Kl[2][64][64];   // swizzled: slot ^= (row^(row>>3))&7
    __shared__ __bf16 Vl[2][64][64];
    __shared__ float  Lbuf[4][32];

    const int tid = threadIdx.x, lane = tid & 63, w = tid >> 6;
    const int c = lane & 31, h = lane >> 5;
    const int bh = blockIdx.y, b = bh >> 3, hd = bh & 7;
    const int qbase = blockIdx.x * 128 + w * 32;
    const int kvoff = SPLIT ? blockIdx.z * (SEQ / 2) : 0;
    const int NT = SPLIT ? (SEQ / 2) / 64 : SEQ / 64;

    bf16x8 qf[4];
#pragma unroll
    for (int t = 0; t < 4; ++t)
        qf[t] = *(const bf16x8*)&Qp[(size_t)(b * SEQ + qbase + c) * DM + hd * DKH + 16 * t + 8 * h];

    const int r0 = w * 16 + (lane >> 3);
    const int r1 = r0 + 8;
    const int s0 = (lane & 7) ^ ((r0 ^ (r0 >> 3)) & 7);
    const int s1 = (lane & 7) ^ ((r1 ^ (r1 >> 3)) & 7);
    const __bf16* kg0 = Kp + (size_t)(b * SEQ + kvoff + r0) * DM + hd * DKH + s0 * 8;
    const __bf16* kg1 = Kp + (size_t)(b * SEQ + kvoff + r1) * DM + hd * DKH + s1 * 8;
    const __bf16* vg0 = Vt + (size_t)(bh * DKH + r0) * SEQ + kvoff + s0 * 8;
    const __bf16* vg1 = Vt + (size_t)(bh * DKH + r1) * SEQ + kvoff + s1 * 8;

    const int swz0 = (c ^ (c >> 3)) & 7;
    const int swz1 = ((32 + c) ^ ((32 + c) >> 3)) & 7;
    const int rowb0 = c * 128, rowb1 = (32 + c) * 128;
    const char* kb = (const char*)&Kl[0][0][0];
    const char* vb = (const char*)&Vl[0][0][0];

    f32x16 acc0 = {}, acc1 = {};
    float m_run = -__builtin_inff(), l_run = 0.f;

    GLD16(kg0, &Kl[0][w * 16][0]);
    GLD16(kg1, &Kl[0][w * 16 + 8][0]);
    GLD16(vg0, &Vl[0][w * 16][0]);
    GLD16(vg1, &Vl[0][w * 16 + 8][0]);
    __syncthreads();

    for (int kvt = 0; kvt < NT; ++kvt) {
        const int cur = kvt & 1;
        if (kvt + 1 < NT) {
            const size_t ko = (size_t)(kvt + 1) * 64 * DM;
            const size_t vo = (size_t)(kvt + 1) * 64;
            GLD16(kg0 + ko, &Kl[cur ^ 1][w * 16][0]);
            GLD16(kg1 + ko, &Kl[cur ^ 1][w * 16 + 8][0]);
            GLD16(vg0 + vo, &Vl[cur ^ 1][w * 16][0]);
            GLD16(vg1 + vo, &Vl[cur ^ 1][w * 16 + 8][0]);
        }
        const char* kc = kb + cur * (64 * 128);
        const char* vc = vb + cur * (64 * 128);

        f32x16 sa = {}, sb = {};
        __builtin_amdgcn_s_setprio(1);
#pragma unroll
        for (int t = 0; t < 4; ++t) {
            bf16x8 kf0 = *(const bf16x8*)(kc + rowb0 + (((2 * t + h) ^ swz0) << 4));
            sa = mfma32(kf0, qf[t], sa);
            bf16x8 kf1 = *(const bf16x8*)(kc + rowb1 + (((2 * t + h) ^ swz1) << 4));
            sb = mfma32(kf1, qf[t], sb);
        }
        __builtin_amdgcn_s_setprio(0);

        float mx = sa[0];
#pragma unroll
        for (int r = 1; r < 16; ++r) mx = fmaxf(mx, sa[r]);
#pragma unroll
        for (int r = 0; r < 16; ++r) mx = fmaxf(mx, sb[r]);
        mx = fmaxf(mx, __shfl_xor(mx, 32));
        if (!__all(mx <= m_run + 8.f)) {
            const float mnew = fmaxf(m_run, mx);
            const float al = __builtin_amdgcn_exp2f(m_run - mnew);
            m_run = mnew;
            l_run *= al;
            if (lane < 32) Lbuf[w][lane] = al;
#pragma unroll
            for (int r = 0; r < 16; ++r) {
                const float a2 = Lbuf[w][(r & 3) + 8 * (r >> 2) + 4 * h];
                acc0[r] *= a2; acc1[r] *= a2;
            }
        }
        float ls = 0.f;
        float pa[16], pb[16];
#pragma unroll
        for (int r = 0; r < 16; ++r) { pa[r] = __builtin_amdgcn_exp2f(sa[r] - m_run); ls += pa[r]; }
#pragma unroll
        for (int r = 0; r < 16; ++r) { pb[r] = __builtin_amdgcn_exp2f(sb[r] - m_run); ls += pb[r]; }
        ls += __shfl_xor(ls, 32);
        l_run += ls;

        // pack P to bf16 pairs: u[q4][i] holds kv {8q4+4h+2i, +1}
        int ua[4][2], ub[4][2];
#pragma unroll
        for (int q4 = 0; q4 < 4; ++q4)
#pragma unroll
            for (int i = 0; i < 2; ++i) {
                bf16x2 ta; ta[0] = (__bf16)pa[4 * q4 + 2 * i]; ta[1] = (__bf16)pa[4 * q4 + 2 * i + 1];
                ua[q4][i] = __builtin_bit_cast(int, ta);
                bf16x2 tb; tb[0] = (__bf16)pb[4 * q4 + 2 * i]; tb[1] = (__bf16)pb[4 * q4 + 2 * i + 1];
                ub[q4][i] = __builtin_bit_cast(int, tb);
            }

        // PV: A-frag words for inst tg via permlane32 swap:
        // swap(u[2t][i], u[2t+1][i]) -> {w_i, w_{i+2}} for both lane-halves
#pragma unroll
        for (int tg = 0; tg < 4; ++tg) {
            int x0, y0, x1, y1;
            if (tg < 2) {
                x0 = ua[2 * tg][0]; y0 = ua[2 * tg + 1][0];
                x1 = ua[2 * tg][1]; y1 = ua[2 * tg + 1][1];
            } else {
                x0 = ub[2 * (tg - 2)][0]; y0 = ub[2 * (tg - 2) + 1][0];
                x1 = ub[2 * (tg - 2)][1]; y1 = ub[2 * (tg - 2) + 1][1];
            }
            asm("v_permlane32_swap_b32 %0, %1" : "+v"(x0), "+v"(y0));
            asm("v_permlane32_swap_b32 %0, %1" : "+v"(x1), "+v"(y1));
            union { int i4[4]; bf16x8 v; } pf;
            pf.i4[0] = x0; pf.i4[1] = x1; pf.i4[2] = y0; pf.i4[3] = y1;
            bf16x8 vf0 = *(const bf16x8*)(vc + rowb0 + (((2 * tg + h) ^ swz0) << 4));
            bf16x8 vf1 = *(const bf16x8*)(vc + rowb1 + (((2 * tg + h) ^ swz1) << 4));
            __builtin_amdgcn_s_setprio(1);
            acc0 = mfma32(pf.v, vf0, acc0);
            acc1 = mfma32(pf.v, vf1, acc1);
            __builtin_amdgcn_s_setprio(0);
        }
        __syncthreads();
    }

    if (SPLIT) {
        __bf16* pp = blockIdx.z ? O1 : O0;
#pragma unroll
        for (int r = 0; r < 16; ++r) {
            const int qr = (r & 3) + 8 * (r >> 2) + 4 * h;
            const size_t off = (size_t)(b * SEQ + qbase + qr) * DM + hd * DKH;
            pp[off + c]      = (__bf16)acc0[r];
            pp[off + 32 + c] = (__bf16)acc1[r];
        }
        if (h == 0) {
            float2 v; v.x = m_run; v.y = l_run;
            ml[(size_t)(blockIdx.z * 16 + bh) * SEQ + qbase + c] = v;
        }
    } else {
        if (lane < 32) Lbuf[w][lane] = l_run;
        __bf16* outp = O0 + (size_t)(b * SEQ + qbase) * DM + hd * DKH;
#pragma unroll
        for (int r = 0; r < 16; ++r) {
            const int qr = (r & 3) + 8 * (r >> 2) + 4 * h;
            const float li = 1.f / Lbuf[w][qr];
            outp[(size_t)qr * DM + c]      = (__bf16)(acc0[r] * li);
            outp[(size_t)qr * DM + 32 + c] = (__bf16)(acc1[r] * li);
        }
    }
}

// ---------------------------------------------------------------------------
// Combine the two kv-half partials:  Ctx = (P0*e0 + P1*e1) / (l0*e0 + l1*e1)
// One block per token row; thread t handles 2 dk columns.
// ---------------------------------------------------------------------------
__global__ __launch_bounds__(256) void combine(const __bf16* __restrict__ P0,
                                               const __bf16* __restrict__ P1,
                                               const float2* __restrict__ ml,
                                               __bf16* __restrict__ Ctx) {
    const int row = blockIdx.x;             // b*SEQ + q
    const int b = row >> 12, q = row & (SEQ - 1);
    const int col = threadIdx.x * 2;
    const int head = col >> 6;
    const int bh = b * HEADS + head;
    const float2 ml0 = ml[(size_t)bh * SEQ + q];
    const float2 ml1 = ml[(size_t)(16 + bh) * SEQ + q];
    const float m = fmaxf(ml0.x, ml1.x);
    const float e0 = __builtin_amdgcn_exp2f(ml0.x - m);
    const float e1 = __builtin_amdgcn_exp2f(ml1.x - m);
    const float inv = 1.f / (ml0.y * e0 + ml1.y * e1);
    const float f0 = e0 * inv, f1 = e1 * inv;
    const size_t idx = (size_t)row * DM + col;
    bf16x2 a = *(const bf16x2*)&P0[idx];
    bf16x2 bb = *(const bf16x2*)&P1[idx];
    bf16x2 o;
    o[0] = (__bf16)((float)a[0] * f0 + (float)bb[0] * f1);
    o[1] = (__bf16)((float)a[1] * f0 + (float)bb[1] * f1);
    *(bf16x2*)&Ctx[idx] = o;
}

// ---------------------------------------------------------------------------
extern "C" void kernel_launch(void* const* d_in, const int* in_sizes, int n_in,
                              void* d_out, int out_size, void* d_ws, size_t ws_size,
                              hipStream_t stream) {
    (void)in_sizes; (void)n_in; (void)out_size;
    const float* query = (const float*)d_in[0];
    const float* key_  = (const float*)d_in[1];
    const float* value = (const float*)d_in[2];
    const float* Wq = (const float*)d_in[3];
    const float* bq = (const float*)d_in[4];
    const float* Wk = (const float*)d_in[5];
    const float* bk = (const float*)d_in[6];
    const float* Wv = (const float*)d_in[7];
    const float* bv = (const float*)d_in[8];
    const float* Wo = (const float*)d_in[9];
    const float* bo = (const float*)d_in[10];

    char* ws = (char*)d_ws;
    const size_t WSZ = (size_t)512 * 1024;        // per transposed weight
    const size_t XSZ = (size_t)8 * 1024 * 1024;   // per [8192][512] bf16 buffer
    const float QSC = 0.125f * 1.4426950408889634f;  // 1/sqrt(dk) * log2(e)

    __bf16* Wtq = (__bf16*)(ws);
    __bf16* Wtk = (__bf16*)(ws + WSZ);
    __bf16* Wtv = (__bf16*)(ws + 2 * WSZ);
    __bf16* Wto = (__bf16*)(ws + 3 * WSZ);
    char* xb = ws + 4 * WSZ;

    WtAll wa;
    wa.W[0] = Wq; wa.W[1] = Wk; wa.W[2] = Wv; wa.W[3] = Wo;
    wa.Wt[0] = Wtq; wa.Wt[1] = Wtk; wa.Wt[2] = Wtv; wa.Wt[3] = Wto;

    if (ws_size >= 4 * WSZ + 7 * XSZ) {
        // ---- main path: bf16 activations + split-kv flash ----
        __bf16* Qb = (__bf16*)(xb);
        __bf16* Kb = (__bf16*)(xb + XSZ);
        __bf16* Vb = (__bf16*)(xb + 2 * XSZ);
        __bf16* Qp = (__bf16*)(xb + 3 * XSZ);
        __bf16* Kp = (__bf16*)(xb + 4 * XSZ);
        __bf16* Vp = (__bf16*)(xb + 5 * XSZ);
        __bf16* Vt = (__bf16*)(xb + 6 * XSZ);
        __bf16* Ctx = Vp;                 // Vp dead after v_transpose
        __bf16* P0 = Qb;                  // Qb/Kb/Vb dead after projections
        __bf16* P1 = Kb;
        float2* mlp = (float2*)Vb;        // needs 1 MB

        Cvt3 cv;
        cv.s[0] = query; cv.s[1] = key_; cv.s[2] = value;
        cv.d[0] = Qb; cv.d[1] = Kb; cv.d[2] = Vb;
        convert_x3<<<dim3(2048, 3), 256, 0, stream>>>(cv);
        wt_convert_all<<<dim3(16, 16, 4), 256, 0, stream>>>(wa);

        GemmArgs qa;
        qa.p[0] = {Qb, Wtq, bq, Qp, QSC};
        qa.p[1] = {Kb, Wtk, bk, Kp, 1.0f};
        qa.p[2] = {Vb, Wtv, bv, Vp, 1.0f};
        gemm_tile<false, true><<<dim3(64, 4, 3), 256, 0, stream>>>(qa);

        v_transpose<<<dim3(SEQ / 64, BATCH * HEADS), 256, 0, stream>>>(Vp, Vt);

        flash_attn3<true><<<dim3(SEQ / 128, BATCH * HEADS, 2), 256, 0, stream>>>(
            Qp, Kp, Vt, P0, P1, mlp);

        combine<<<dim3(BATCH * SEQ), 256, 0, stream>>>(P0, P1, mlp, Ctx);

        GemmArgs oa;
        oa.p[0] = {Ctx, Wto, bo, d_out, 1.0f};
        oa.p[1] = oa.p[0]; oa.p[2] = oa.p[0];
        gemm_tile<false, false><<<dim3(64, 4, 1), 256, 0, stream>>>(oa);
    } else {
        // ---- fallback: fp32-A GEMM staging, single-pass flash ----
        if (ws_size < 4 * WSZ + 4 * XSZ) return;
        __bf16* Qp = (__bf16*)(xb);
        __bf16* Kp = (__bf16*)(xb + XSZ);
        __bf16* Vp = (__bf16*)(xb + 2 * XSZ);
        __bf16* Vt = (__bf16*)(xb + 3 * XSZ);
        __bf16* Ctx = Vp;

        wt_convert_all<<<dim3(16, 16, 4), 256, 0, stream>>>(wa);

        GemmArgs qa;
        qa.p[0] = {query, Wtq, bq, Qp, QSC};
        qa.p[1] = {key_,  Wtk, bk, Kp, 1.0f};
        qa.p[2] = {value, Wtv, bv, Vp, 1.0f};
        gemm_tile<true, true><<<dim3(64, 4, 3), 256, 0, stream>>>(qa);

        v_transpose<<<dim3(SEQ / 64, BATCH * HEADS), 256, 0, stream>>>(Vp, Vt);

        flash_attn3<false><<<dim3(SEQ / 128, BATCH * HEADS, 1), 256, 0, stream>>>(
            Qp, Kp, Vt, Ctx, nullptr, nullptr);

        GemmArgs oa;
        oa.p[0] = {Ctx, Wto, bo, d_out, 1.0f};
        oa.p[1] = oa.p[0]; oa.p[2] = oa.p[0];
        gemm_tile<false, false><<<dim3(64, 4, 1), 256, 0, stream>>>(oa);
    }
}